// Round 2
// baseline (642.156 us; speedup 1.0000x reference)
//
#include <hip/hip_runtime.h>

#define BB 8
#define LLEN 896
#define DMODEL 320
#define NHEAD 10
#define DHEAD 32
#define DINNER 1280
#define ROWS (BB*LLEN)   // 7168

typedef float f32x4 __attribute__((ext_vector_type(4)));
typedef __bf16 bf16x8 __attribute__((ext_vector_type(8)));
typedef short s16x8 __attribute__((ext_vector_type(8)));

__device__ __forceinline__ float bf2f(unsigned short u) {
    union { unsigned int i; float f; } x;
    x.i = ((unsigned int)u) << 16;
    return x.f;
}
__device__ __forceinline__ unsigned short f2bf(float f) {
    unsigned int u = __float_as_uint(f);
    u += 0x7FFF + ((u >> 16) & 1);   // round-to-nearest-even
    return (unsigned short)(u >> 16);
}

// ---------------- weight transpose fp32 -> bf16 (dst[C][R] = src[R][C]) ----------------
__global__ __launch_bounds__(256) void transpose_bf16(const float* __restrict__ src,
                                                      unsigned short* __restrict__ dst,
                                                      int R, int C) {
    __shared__ float tile[32][33];
    int c0 = blockIdx.x * 32;
    int r0 = blockIdx.y * 32;
    int tx = threadIdx.x & 31, ty = threadIdx.x >> 5;  // ty 0..7
#pragma unroll
    for (int k = 0; k < 4; ++k) {
        int yy = ty + 8 * k;
        tile[yy][tx] = src[(size_t)(r0 + yy) * C + c0 + tx];
    }
    __syncthreads();
#pragma unroll
    for (int k = 0; k < 4; ++k) {
        int yy = ty + 8 * k;
        dst[(size_t)(c0 + yy) * R + r0 + tx] = f2bf(tile[tx][yy]);
    }
}

// ---------------- LayerNorm (fp32 in, bf16 out), one row per block, 320 threads ----------------
__global__ __launch_bounds__(320) void ln_kernel(const float* __restrict__ x,
                                                 const float* __restrict__ g,
                                                 const float* __restrict__ bia,
                                                 unsigned short* __restrict__ y) {
    int row = blockIdx.x;
    int t = threadIdx.x;
    float v = x[(size_t)row * DMODEL + t];
    float s = v;
#pragma unroll
    for (int o = 1; o < 64; o <<= 1) s += __shfl_xor(s, o, 64);
    __shared__ float red[10];
    int w = t >> 6;
    if ((t & 63) == 0) red[w] = s;
    __syncthreads();
    float mu = (red[0] + red[1] + red[2] + red[3] + red[4]) * (1.0f / DMODEL);
    float d = v - mu;
    float s2 = d * d;
#pragma unroll
    for (int o = 1; o < 64; o <<= 1) s2 += __shfl_xor(s2, o, 64);
    if ((t & 63) == 0) red[5 + w] = s2;
    __syncthreads();
    float var = (red[5] + red[6] + red[7] + red[8] + red[9]) * (1.0f / DMODEL);
    float inv = rsqrtf(var + 1e-5f);
    y[(size_t)row * DMODEL + t] = f2bf(d * inv * g[t] + bia[t]);
}

// ---------------- bf16 MFMA GEMM: A (MxK) @ BT(NxK)^T, 64x64 tile, 4 waves ----------------
// EPI: 0 = +bias -> bf16 ; 1 = +resid(f32) -> f32 ; 2 = +bias,relu -> bf16 ; 3 = +bias+resid -> f32
template <int EPI>
__global__ __launch_bounds__(256) void gemm_bt(const unsigned short* __restrict__ A,
                                               const unsigned short* __restrict__ BT,
                                               const float* __restrict__ bias,
                                               const float* __restrict__ resid,
                                               void* __restrict__ outv,
                                               int M, int N, int K) {
    __shared__ unsigned short As[64][40];  // +8 pad: row pitch 80B = 5*16B
    __shared__ unsigned short Bs[64][40];
    int tid = threadIdx.x;
    int m0 = blockIdx.x * 64;
    int n0 = blockIdx.y * 64;
    int wid = tid >> 6, l = tid & 63;
    int wr = wid >> 1, wc = wid & 1;
    int sr = tid >> 2, sc = (tid & 3) * 8;
    int lr = l & 15, lh = l >> 4;
    f32x4 acc00 = {0.f, 0.f, 0.f, 0.f}, acc01 = acc00, acc10 = acc00, acc11 = acc00;

    for (int k0 = 0; k0 < K; k0 += 32) {
        __syncthreads();
        *(int4*)&As[sr][sc] = *(const int4*)&A[(size_t)(m0 + sr) * K + k0 + sc];
        *(int4*)&Bs[sr][sc] = *(const int4*)&BT[(size_t)(n0 + sr) * K + k0 + sc];
        __syncthreads();
        bf16x8 a0 = *(const bf16x8*)&As[wr * 32 + lr][lh * 8];
        bf16x8 a1 = *(const bf16x8*)&As[wr * 32 + 16 + lr][lh * 8];
        bf16x8 b0 = *(const bf16x8*)&Bs[wc * 32 + lr][lh * 8];
        bf16x8 b1 = *(const bf16x8*)&Bs[wc * 32 + 16 + lr][lh * 8];
        acc00 = __builtin_amdgcn_mfma_f32_16x16x32_bf16(a0, b0, acc00, 0, 0, 0);
        acc01 = __builtin_amdgcn_mfma_f32_16x16x32_bf16(a0, b1, acc01, 0, 0, 0);
        acc10 = __builtin_amdgcn_mfma_f32_16x16x32_bf16(a1, b0, acc10, 0, 0, 0);
        acc11 = __builtin_amdgcn_mfma_f32_16x16x32_bf16(a1, b1, acc11, 0, 0, 0);
    }

    unsigned short* outb = (unsigned short*)outv;
    float* outf = (float*)outv;
#pragma unroll
    for (int mi = 0; mi < 2; ++mi)
#pragma unroll
        for (int ni = 0; ni < 2; ++ni) {
            f32x4 a = (mi == 0) ? ((ni == 0) ? acc00 : acc01) : ((ni == 0) ? acc10 : acc11);
            int col = n0 + wc * 32 + ni * 16 + lr;
#pragma unroll
            for (int j = 0; j < 4; ++j) {
                int row = m0 + wr * 32 + mi * 16 + lh * 4 + j;
                float v = a[j];
                if (EPI == 0 || EPI == 2 || EPI == 3) v += bias[col];
                if (EPI == 2) v = fmaxf(v, 0.0f);
                if (EPI == 1 || EPI == 3) v += resid[(size_t)row * N + col];
                if (EPI == 0 || EPI == 2) outb[(size_t)row * N + col] = f2bf(v);
                else outf[(size_t)row * N + col] = v;
            }
        }
}

// ---------------- fused attention (fp32 math, bf16 K/V/Q from qkv buffer) ----------------
// qkv row layout per head h: [V:0..31 | Q:32..63 | K:64..95] at col h*96.
// Block: one (b,h,ntile of 64 rows). 256 threads; thread owns row (tid&63),
// quarter q=tid>>6 processes m-tiles q,4+q,8+q,12+q (64 m each). Online softmax,
// post-softmax mask folded into numerator. Quarter-combine via LDS.
__global__ __launch_bounds__(256) void attn_kernel(const unsigned short* __restrict__ qkv,
                                                   const float* __restrict__ Dm,
                                                   const float* __restrict__ nmask,
                                                   const float* __restrict__ mask,
                                                   const float* __restrict__ gamma,
                                                   unsigned short* __restrict__ attn) {
    union __align__(16) U {
        struct { unsigned short K[4][64][32]; unsigned short V[4][64][32]; } kv;  // 32 KB
        float comb[4][34][64];                                                    // 34.8 KB
    };
    __shared__ U u;

    int tid = threadIdx.x;
    int bid = blockIdx.x;          // (b*NHEAD + h)*14 + nt
    int nt = bid % 14;
    int bh = bid / 14;
    int h = bh % NHEAD;
    int b = bh / NHEAD;
    int rl = tid & 63, q = tid >> 6;
    int n = nt * 64 + rl;

    size_t zrow = (size_t)(b * LLEN + n) * (3 * DMODEL) + h * 96;
    float Q[32];
#pragma unroll
    for (int c = 0; c < 4; ++c) {
        s16x8 qv = *(const s16x8*)&qkv[zrow + 32 + c * 8];
#pragma unroll
        for (int e = 0; e < 8; ++e)
            Q[c * 8 + e] = bf2f((unsigned short)qv[e]) * 0.17677669529663687f;  // 1/sqrt(32)
    }
    int segn = (n < 128) ? 0 : (n < 384) ? 1 : 2;
    float gn0 = gamma[segn * 4 + 0], gn1 = gamma[segn * 4 + 1], gn2 = gamma[segn * 4 + 2];
    const float* Drow = Dm + (size_t)(b * LLEN + n) * LLEN;
    const float* Nrow = nmask + (size_t)(b * LLEN + n) * LLEN;
    const float* Mrow = mask + (size_t)(b * LLEN + n) * LLEN;

    float mx = -3.0e38f, sum = 0.f;
    float acc[32];
#pragma unroll
    for (int d = 0; d < 32; ++d) acc[d] = 0.f;

    for (int rnd = 0; rnd < 4; ++rnd) {
        __syncthreads();
        {   // stage: thread stages row rl of tile (4*rnd + q)
            int tglob = 4 * rnd + q;
            if (tglob < 14) {
                int mg = tglob * 64 + rl;
                size_t src = (size_t)(b * LLEN + mg) * (3 * DMODEL) + h * 96;
#pragma unroll
                for (int c = 0; c < 4; ++c) {
                    *(int4*)&u.kv.V[q][rl][c * 8] = *(const int4*)&qkv[src + c * 8];
                    *(int4*)&u.kv.K[q][rl][c * 8] = *(const int4*)&qkv[src + 64 + c * 8];
                }
            }
        }
        __syncthreads();
        int tt = 4 * rnd + q;
        if (tt < 14) {
#pragma unroll 1
            for (int mc = 0; mc < 16; ++mc) {
                int mbase = tt * 64 + mc * 4;
                float4 d4 = *(const float4*)&Drow[mbase];
                float4 nm4 = *(const float4*)&Nrow[mbase];
                float4 mk4 = *(const float4*)&Mrow[mbase];
                float dv[4] = {d4.x, d4.y, d4.z, d4.w};
                float nv[4] = {nm4.x, nm4.y, nm4.z, nm4.w};
                float mv[4] = {mk4.x, mk4.y, mk4.z, mk4.w};
#pragma unroll
                for (int j = 0; j < 4; ++j) {
                    int mm = mc * 4 + j;
                    int mg = mbase + j;
                    float g = (mg < 128) ? gn0 : ((mg < 384) ? gn1 : gn2);
                    float s0 = 0, s1 = 0, s2 = 0, s3 = 0;
                    const unsigned short* kr = &u.kv.K[q][mm][0];
#pragma unroll
                    for (int c = 0; c < 4; ++c) {
                        s16x8 kv8 = *(const s16x8*)(kr + c * 8);
                        s0 += Q[c * 8 + 0] * bf2f((unsigned short)kv8[0]);
                        s1 += Q[c * 8 + 1] * bf2f((unsigned short)kv8[1]);
                        s2 += Q[c * 8 + 2] * bf2f((unsigned short)kv8[2]);
                        s3 += Q[c * 8 + 3] * bf2f((unsigned short)kv8[3]);
                        s0 += Q[c * 8 + 4] * bf2f((unsigned short)kv8[4]);
                        s1 += Q[c * 8 + 5] * bf2f((unsigned short)kv8[5]);
                        s2 += Q[c * 8 + 6] * bf2f((unsigned short)kv8[6]);
                        s3 += Q[c * 8 + 7] * bf2f((unsigned short)kv8[7]);
                    }
                    float s = ((s0 + s1) + (s2 + s3)) - g * dv[j] + nv[j];
                    if (s > mx) {
                        float so = __expf(mx - s);
                        sum *= so;
#pragma unroll
                        for (int d2 = 0; d2 < 32; ++d2) acc[d2] *= so;
                        mx = s;
                    }
                    float e = __expf(s - mx);
                    sum += e;
                    float ev = e * mv[j];
                    const unsigned short* vr = &u.kv.V[q][mm][0];
#pragma unroll
                    for (int c = 0; c < 4; ++c) {
                        s16x8 vv8 = *(const s16x8*)(vr + c * 8);
#pragma unroll
                        for (int e2 = 0; e2 < 8; ++e2)
                            acc[c * 8 + e2] += ev * bf2f((unsigned short)vv8[e2]);
                    }
                }
            }
        }
    }

    __syncthreads();
    u.comb[q][0][rl] = mx;
    u.comb[q][1][rl] = sum;
#pragma unroll
    for (int d = 0; d < 32; ++d) u.comb[q][2 + d][rl] = acc[d];
    __syncthreads();

    float m0v = u.comb[0][0][rl], m1v = u.comb[1][0][rl];
    float m2v = u.comb[2][0][rl], m3v = u.comb[3][0][rl];
    float mst = fmaxf(fmaxf(m0v, m1v), fmaxf(m2v, m3v));
    float w0 = __expf(m0v - mst), w1 = __expf(m1v - mst);
    float w2 = __expf(m2v - mst), w3 = __expf(m3v - mst);
    float ssum = u.comb[0][1][rl] * w0 + u.comb[1][1][rl] * w1 +
                 u.comb[2][1][rl] * w2 + u.comb[3][1][rl] * w3;
    float inv = 1.0f / ssum;
    size_t obase = (size_t)(b * LLEN + n) * DMODEL + h * DHEAD;
#pragma unroll
    for (int dd = 0; dd < 8; ++dd) {
        int d = q * 8 + dd;
        float o = (u.comb[0][2 + d][rl] * w0 + u.comb[1][2 + d][rl] * w1 +
                   u.comb[2][2 + d][rl] * w2 + u.comb[3][2 + d][rl] * w3) * inv;
        o = (o >= 0.f) ? o : 0.01f * o;  // leaky_relu(0.01)
        attn[obase + d] = f2bf(o);
    }
}

// ---------------- launch ----------------
extern "C" void kernel_launch(void* const* d_in, const int* in_sizes, int n_in,
                              void* d_out, int out_size, void* d_ws, size_t ws_size,
                              hipStream_t stream) {
    const float* Z     = (const float*)d_in[0];
    const float* Dm    = (const float*)d_in[1];
    const float* nmask = (const float*)d_in[2];
    const float* mask  = (const float*)d_in[3];
    const float* gamma = (const float*)d_in[4];
    const float* w_qkv = (const float*)d_in[5];
    const float* b_qkv = (const float*)d_in[6];
    const float* w_o   = (const float*)d_in[7];
    const float* ln1g  = (const float*)d_in[8];
    const float* ln1b  = (const float*)d_in[9];
    const float* ln2g  = (const float*)d_in[10];
    const float* ln2b  = (const float*)d_in[11];
    const float* w1    = (const float*)d_in[12];
    const float* b1    = (const float*)d_in[13];
    const float* w2    = (const float*)d_in[14];
    const float* b2    = (const float*)d_in[15];

    char* ws = (char*)d_ws;
    unsigned short* Zn    = (unsigned short*)(ws + 0);         // 7168x320 bf16
    unsigned short* qkv   = (unsigned short*)(ws + 4587520);   // 7168x960 bf16
    unsigned short* attn  = (unsigned short*)(ws + 18350080);  // 7168x320 bf16
    float*          Zres  = (float*)(ws + 22937600);           // 7168x320 f32
    unsigned short* Zn2   = (unsigned short*)(ws + 32112640);  // 7168x320 bf16
    unsigned short* Hbuf  = (unsigned short*)(ws + 36700160);  // 7168x1280 bf16
    unsigned short* wqkvT = (unsigned short*)(ws + 55050240);  // 960x320 bf16
    unsigned short* woT   = (unsigned short*)(ws + 55664640);  // 320x320 bf16
    unsigned short* w1T   = (unsigned short*)(ws + 55869440);  // 1280x320 bf16
    unsigned short* w2T   = (unsigned short*)(ws + 56688640);  // 320x1280 bf16

    // weight prep
    transpose_bf16<<<dim3(960 / 32, 320 / 32), 256, 0, stream>>>(w_qkv, wqkvT, 320, 960);
    transpose_bf16<<<dim3(320 / 32, 320 / 32), 256, 0, stream>>>(w_o, woT, 320, 320);
    transpose_bf16<<<dim3(1280 / 32, 320 / 32), 256, 0, stream>>>(w1, w1T, 320, 1280);
    transpose_bf16<<<dim3(320 / 32, 1280 / 32), 256, 0, stream>>>(w2, w2T, 1280, 320);

    // LN1
    ln_kernel<<<ROWS, 320, 0, stream>>>(Z, ln1g, ln1b, Zn);

    // QKV GEMM: Zn(7168x320) @ w_qkv(320x960) + b_qkv -> qkv bf16
    gemm_bt<0><<<dim3(ROWS / 64, 960 / 64), 256, 0, stream>>>(Zn, wqkvT, b_qkv, nullptr,
                                                              (void*)qkv, ROWS, 960, 320);

    // attention -> leaky_relu -> attn bf16
    attn_kernel<<<BB * NHEAD * 14, 256, 0, stream>>>(qkv, Dm, nmask, mask, gamma, attn);

    // W_O GEMM + residual Z -> Zres f32
    gemm_bt<1><<<dim3(ROWS / 64, 320 / 64), 256, 0, stream>>>(attn, woT, nullptr, Z,
                                                              (void*)Zres, ROWS, 320, 320);

    // LN2
    ln_kernel<<<ROWS, 320, 0, stream>>>(Zres, ln2g, ln2b, Zn2);

    // FFN1: Zn2 @ w1 + b1, relu -> H bf16
    gemm_bt<2><<<dim3(ROWS / 64, 1280 / 64), 256, 0, stream>>>(Zn2, w1T, b1, nullptr,
                                                               (void*)Hbuf, ROWS, 1280, 320);

    // FFN2: H @ w2 + b2 + Zres -> out f32
    gemm_bt<3><<<dim3(ROWS / 64, 320 / 64), 256, 0, stream>>>(Hbuf, w2T, b2, Zres,
                                                              d_out, ROWS, 320, 1280);
}

// Round 3
// 300.151 us; speedup vs baseline: 2.1394x; 2.1394x over previous
//
#include <hip/hip_runtime.h>

#define BB 8
#define LLEN 896
#define DMODEL 320
#define NHEAD 10
#define DHEAD 32
#define DINNER 1280
#define ROWS (BB*LLEN)   // 7168

typedef float f32x4 __attribute__((ext_vector_type(4)));
typedef float f32x16 __attribute__((ext_vector_type(16)));
typedef __bf16 bf16x8 __attribute__((ext_vector_type(8)));
typedef short s16x8 __attribute__((ext_vector_type(8)));

__device__ __forceinline__ float bf2f(unsigned short u) {
    union { unsigned int i; float f; } x;
    x.i = ((unsigned int)u) << 16;
    return x.f;
}
__device__ __forceinline__ unsigned short f2bf(float f) {
    unsigned int u = __float_as_uint(f);
    u += 0x7FFF + ((u >> 16) & 1);   // round-to-nearest-even
    return (unsigned short)(u >> 16);
}

// ---------------- weight transpose fp32 -> bf16 (dst[C][R] = src[R][C]) ----------------
__global__ __launch_bounds__(256) void transpose_bf16(const float* __restrict__ src,
                                                      unsigned short* __restrict__ dst,
                                                      int R, int C) {
    __shared__ float tile[32][33];
    int c0 = blockIdx.x * 32;
    int r0 = blockIdx.y * 32;
    int tx = threadIdx.x & 31, ty = threadIdx.x >> 5;  // ty 0..7
#pragma unroll
    for (int k = 0; k < 4; ++k) {
        int yy = ty + 8 * k;
        tile[yy][tx] = src[(size_t)(r0 + yy) * C + c0 + tx];
    }
    __syncthreads();
#pragma unroll
    for (int k = 0; k < 4; ++k) {
        int yy = ty + 8 * k;
        dst[(size_t)(c0 + yy) * R + r0 + tx] = f2bf(tile[tx][yy]);
    }
}

// ---------------- mask/bias pre-pass: combo[b][m][n] = bf16(-g*D+nmask) | bf16(mask)<<16 ----
__global__ __launch_bounds__(256) void prepass(const float* __restrict__ D,
                                               const float* __restrict__ nm,
                                               const float* __restrict__ mk,
                                               const float* __restrict__ gamma,
                                               unsigned int* __restrict__ combo) {
    __shared__ unsigned int tile[32][33];
    int m0 = blockIdx.x * 32;
    int n0 = blockIdx.y * 32;
    int b = blockIdx.z;
    int sn = (n0 < 128) ? 0 : (n0 < 384) ? 1 : 2;   // 32-tiles never straddle 128/384
    int sm = (m0 < 128) ? 0 : (m0 < 384) ? 1 : 2;
    float g = gamma[sn * 4 + sm];
    int tx = threadIdx.x & 31, ty = threadIdx.x >> 5;
#pragma unroll
    for (int k = 0; k < 4; ++k) {
        int nl = ty + 8 * k;
        size_t idx = ((size_t)b * LLEN + n0 + nl) * LLEN + m0 + tx;
        float bias = -g * D[idx] + nm[idx];
        tile[nl][tx] = (unsigned int)f2bf(bias) | ((unsigned int)f2bf(mk[idx]) << 16);
    }
    __syncthreads();
#pragma unroll
    for (int k = 0; k < 4; ++k) {
        int ml = ty + 8 * k;
        combo[((size_t)b * LLEN + m0 + ml) * LLEN + n0 + tx] = tile[tx][ml];
    }
}

// ---------------- LayerNorm (fp32 in, bf16 out), one row per block, 320 threads ----------------
__global__ __launch_bounds__(320) void ln_kernel(const float* __restrict__ x,
                                                 const float* __restrict__ g,
                                                 const float* __restrict__ bia,
                                                 unsigned short* __restrict__ y) {
    int row = blockIdx.x;
    int t = threadIdx.x;
    float v = x[(size_t)row * DMODEL + t];
    float s = v;
#pragma unroll
    for (int o = 1; o < 64; o <<= 1) s += __shfl_xor(s, o, 64);
    __shared__ float red[10];
    int w = t >> 6;
    if ((t & 63) == 0) red[w] = s;
    __syncthreads();
    float mu = (red[0] + red[1] + red[2] + red[3] + red[4]) * (1.0f / DMODEL);
    float d = v - mu;
    float s2 = d * d;
#pragma unroll
    for (int o = 1; o < 64; o <<= 1) s2 += __shfl_xor(s2, o, 64);
    if ((t & 63) == 0) red[5 + w] = s2;
    __syncthreads();
    float var = (red[5] + red[6] + red[7] + red[8] + red[9]) * (1.0f / DMODEL);
    float inv = rsqrtf(var + 1e-5f);
    y[(size_t)row * DMODEL + t] = f2bf(d * inv * g[t] + bia[t]);
}

// ---------------- bf16 MFMA GEMM: A (MxK) @ BT(NxK)^T, 64x64 tile, 4 waves ----------------
// EPI: 0 = +bias -> bf16 ; 1 = +resid(f32) -> f32 ; 2 = +bias,relu -> bf16 ; 3 = +bias+resid -> f32
template <int EPI>
__global__ __launch_bounds__(256) void gemm_bt(const unsigned short* __restrict__ A,
                                               const unsigned short* __restrict__ BT,
                                               const float* __restrict__ bias,
                                               const float* __restrict__ resid,
                                               void* __restrict__ outv,
                                               int M, int N, int K) {
    __shared__ unsigned short As[64][40];  // +8 pad: row pitch 80B = 5*16B
    __shared__ unsigned short Bs[64][40];
    int tid = threadIdx.x;
    int m0 = blockIdx.x * 64;
    int n0 = blockIdx.y * 64;
    int wid = tid >> 6, l = tid & 63;
    int wr = wid >> 1, wc = wid & 1;
    int sr = tid >> 2, sc = (tid & 3) * 8;
    int lr = l & 15, lh = l >> 4;
    f32x4 acc00 = {0.f, 0.f, 0.f, 0.f}, acc01 = acc00, acc10 = acc00, acc11 = acc00;

    for (int k0 = 0; k0 < K; k0 += 32) {
        __syncthreads();
        *(int4*)&As[sr][sc] = *(const int4*)&A[(size_t)(m0 + sr) * K + k0 + sc];
        *(int4*)&Bs[sr][sc] = *(const int4*)&BT[(size_t)(n0 + sr) * K + k0 + sc];
        __syncthreads();
        bf16x8 a0 = *(const bf16x8*)&As[wr * 32 + lr][lh * 8];
        bf16x8 a1 = *(const bf16x8*)&As[wr * 32 + 16 + lr][lh * 8];
        bf16x8 b0 = *(const bf16x8*)&Bs[wc * 32 + lr][lh * 8];
        bf16x8 b1 = *(const bf16x8*)&Bs[wc * 32 + 16 + lr][lh * 8];
        acc00 = __builtin_amdgcn_mfma_f32_16x16x32_bf16(a0, b0, acc00, 0, 0, 0);
        acc01 = __builtin_amdgcn_mfma_f32_16x16x32_bf16(a0, b1, acc01, 0, 0, 0);
        acc10 = __builtin_amdgcn_mfma_f32_16x16x32_bf16(a1, b0, acc10, 0, 0, 0);
        acc11 = __builtin_amdgcn_mfma_f32_16x16x32_bf16(a1, b1, acc11, 0, 0, 0);
    }

    unsigned short* outb = (unsigned short*)outv;
    float* outf = (float*)outv;
#pragma unroll
    for (int mi = 0; mi < 2; ++mi)
#pragma unroll
        for (int ni = 0; ni < 2; ++ni) {
            f32x4 a = (mi == 0) ? ((ni == 0) ? acc00 : acc01) : ((ni == 0) ? acc10 : acc11);
            int col = n0 + wc * 32 + ni * 16 + lr;
#pragma unroll
            for (int j = 0; j < 4; ++j) {
                int row = m0 + wr * 32 + mi * 16 + lh * 4 + j;
                float v = a[j];
                if (EPI == 0 || EPI == 2 || EPI == 3) v += bias[col];
                if (EPI == 2) v = fmaxf(v, 0.0f);
                if (EPI == 1 || EPI == 3) v += resid[(size_t)row * N + col];
                if (EPI == 0 || EPI == 2) outb[(size_t)row * N + col] = f2bf(v);
                else outf[(size_t)row * N + col] = v;
            }
        }
}

// ---------------- MFMA attention ----------------
// Block = (b, 32-row n-tile), 640 threads = 10 waves, wave w = head w.
// Swapped QK^T: S^T[m][n] = mfma(A=K[32m x 32d], B=Q^T[32d x 32n]) via 2x 32x32x16.
//   C layout (verified m74/m101): col = lane&31 (=n), row m = (r&3)+8*(r>>2)+4*(lane>>5).
// No online max (scores bounded, fp32 exp safe). lsum lane-local + one xor-32 shuffle.
// P -> A-fragment of PV via pack-pairs + __shfl_xor(32) half-exchange.
// PV: O[n][d] = mfma(A=P[32n x 32m], B=V[32m x 32d]) via 2x K=16.
__global__ __launch_bounds__(640) void attn_mfma(const unsigned short* __restrict__ qkv,
                                                 const unsigned int* __restrict__ combo,
                                                 unsigned short* __restrict__ attn) {
    int tid = threadIdx.x;
    int h = tid >> 6;           // head = wave
    int l = tid & 63;
    int c = l & 31;
    int hi = l >> 5;
    int nt = blockIdx.x % 28;
    int b = blockIdx.x / 28;
    int n0 = nt * 32;

    // Q as B-fragment: B[k=d][col=n]: lane needs Q[n0+c][kk*16 + hi*8 + e]
    size_t qbase = ((size_t)(b * LLEN + n0 + c)) * 960 + h * 96 + 32 + hi * 8;
    bf16x8 qB0 = *(const bf16x8*)&qkv[qbase];
    bf16x8 qB1 = *(const bf16x8*)&qkv[qbase + 16];

    f32x16 oacc = {0.f,0.f,0.f,0.f,0.f,0.f,0.f,0.f,0.f,0.f,0.f,0.f,0.f,0.f,0.f,0.f};
    float lsum = 0.f;

    const unsigned int* crow = combo + (size_t)b * LLEN * LLEN + n0 + c;   // + m*896
    size_t kbase = (size_t)b * LLEN * 960 + h * 96 + 64 + hi * 8;          // + m*960
    size_t vbase = (size_t)b * LLEN * 960 + h * 96 + c;                    // + m*960

    for (int mt = 0; mt < 28; ++mt) {
        // K as A-fragment: A[row=m][k=d]: lane: m = mt*32 + c, d = kk*16 + hi*8 + e
        size_t krow = kbase + (size_t)(mt * 32 + c) * 960;
        bf16x8 kA0 = *(const bf16x8*)&qkv[krow];
        bf16x8 kA1 = *(const bf16x8*)&qkv[krow + 16];
        f32x16 sacc = {0.f,0.f,0.f,0.f,0.f,0.f,0.f,0.f,0.f,0.f,0.f,0.f,0.f,0.f,0.f,0.f};
        sacc = __builtin_amdgcn_mfma_f32_32x32x16_bf16(kA0, qB0, sacc, 0, 0, 0);
        sacc = __builtin_amdgcn_mfma_f32_32x32x16_bf16(kA1, qB1, sacc, 0, 0, 0);

        // bias + exp + mask; p[r] for n=c, m = mt*32 + (r&3)+8*(r>>2)+4*hi
        float p[16];
#pragma unroll
        for (int r = 0; r < 16; ++r) {
            int m = mt * 32 + (r & 3) + 8 * (r >> 2) + 4 * hi;
            unsigned int cm = crow[(size_t)m * LLEN];
            float bias = bf2f((unsigned short)(cm & 0xffffu));
            float mk = bf2f((unsigned short)(cm >> 16));
            float s = fmaf(sacc[r], 0.17677669529663687f, bias);   // 1/sqrt(32)
            float e = __expf(s);
            lsum += e;
            p[r] = e * mk;
        }

        // pack pairs (consecutive m) and exchange halves
        unsigned int u[8], x[8];
#pragma unroll
        for (int j = 0; j < 8; ++j) {
            u[j] = (unsigned int)f2bf(p[2 * j]) | ((unsigned int)f2bf(p[2 * j + 1]) << 16);
            x[j] = (unsigned int)__shfl_xor((int)u[j], 32, 64);
        }
        union { unsigned int w[4]; bf16x8 v; } a1, a2;
        if (hi == 0) {
            a1.w[0] = u[0]; a1.w[1] = u[1]; a1.w[2] = x[0]; a1.w[3] = x[1];
            a2.w[0] = u[4]; a2.w[1] = u[5]; a2.w[2] = x[4]; a2.w[3] = x[5];
        } else {
            a1.w[0] = x[2]; a1.w[1] = x[3]; a1.w[2] = u[2]; a1.w[3] = u[3];
            a2.w[0] = x[6]; a2.w[1] = x[7]; a2.w[2] = u[6]; a2.w[3] = u[7];
        }

        // V as B-fragment: B[k=m_loc][col=d]: lane: d = c, m_loc = hi*8 + e (+16 for 2nd)
        union { unsigned short s[8]; bf16x8 v; } v1, v2;
#pragma unroll
        for (int e = 0; e < 8; ++e) {
            v1.s[e] = qkv[vbase + (size_t)(mt * 32 + hi * 8 + e) * 960];
            v2.s[e] = qkv[vbase + (size_t)(mt * 32 + 16 + hi * 8 + e) * 960];
        }
        oacc = __builtin_amdgcn_mfma_f32_32x32x16_bf16(a1.v, v1.v, oacc, 0, 0, 0);
        oacc = __builtin_amdgcn_mfma_f32_32x32x16_bf16(a2.v, v2.v, oacc, 0, 0, 0);
    }

    lsum += __shfl_xor(lsum, 32, 64);
    __shared__ float ls[NHEAD][32];
    ls[h][c] = 1.0f / lsum;
    __syncthreads();
#pragma unroll
    for (int r = 0; r < 16; ++r) {
        int n = (r & 3) + 8 * (r >> 2) + 4 * hi;
        float o = oacc[r] * ls[h][n];
        o = (o >= 0.f) ? o : 0.01f * o;   // leaky_relu(0.01)
        attn[((size_t)(b * LLEN + n0 + n)) * DMODEL + h * DHEAD + c] = f2bf(o);
    }
}

// ---------------- launch ----------------
extern "C" void kernel_launch(void* const* d_in, const int* in_sizes, int n_in,
                              void* d_out, int out_size, void* d_ws, size_t ws_size,
                              hipStream_t stream) {
    const float* Z     = (const float*)d_in[0];
    const float* Dm    = (const float*)d_in[1];
    const float* nmask = (const float*)d_in[2];
    const float* mask  = (const float*)d_in[3];
    const float* gamma = (const float*)d_in[4];
    const float* w_qkv = (const float*)d_in[5];
    const float* b_qkv = (const float*)d_in[6];
    const float* w_o   = (const float*)d_in[7];
    const float* ln1g  = (const float*)d_in[8];
    const float* ln1b  = (const float*)d_in[9];
    const float* ln2g  = (const float*)d_in[10];
    const float* ln2b  = (const float*)d_in[11];
    const float* w1    = (const float*)d_in[12];
    const float* b1    = (const float*)d_in[13];
    const float* w2    = (const float*)d_in[14];
    const float* b2    = (const float*)d_in[15];

    char* ws = (char*)d_ws;
    unsigned short* Zn    = (unsigned short*)(ws + 0);         // 7168x320 bf16
    unsigned short* qkv   = (unsigned short*)(ws + 4587520);   // 7168x960 bf16
    unsigned short* attn  = (unsigned short*)(ws + 18350080);  // 7168x320 bf16
    float*          Zres  = (float*)(ws + 22937600);           // 7168x320 f32
    unsigned short* Zn2   = (unsigned short*)(ws + 32112640);  // 7168x320 bf16
    unsigned short* Hbuf  = (unsigned short*)(ws + 36700160);  // 7168x1280 bf16
    unsigned short* wqkvT = (unsigned short*)(ws + 55050240);  // 960x320 bf16
    unsigned short* woT   = (unsigned short*)(ws + 55664640);  // 320x320 bf16
    unsigned short* w1T   = (unsigned short*)(ws + 55869440);  // 1280x320 bf16
    unsigned short* w2T   = (unsigned short*)(ws + 56688640);  // 320x1280 bf16
    unsigned int*   combo = (unsigned int*)(ws + 57507840);    // 8x896x896 u32 (25.7MB)

    // weight prep
    transpose_bf16<<<dim3(960 / 32, 320 / 32), 256, 0, stream>>>(w_qkv, wqkvT, 320, 960);
    transpose_bf16<<<dim3(320 / 32, 320 / 32), 256, 0, stream>>>(w_o, woT, 320, 320);
    transpose_bf16<<<dim3(1280 / 32, 320 / 32), 256, 0, stream>>>(w1, w1T, 320, 1280);
    transpose_bf16<<<dim3(320 / 32, 1280 / 32), 256, 0, stream>>>(w2, w2T, 1280, 320);

    // mask/bias pre-pass (head-independent, read once)
    prepass<<<dim3(28, 28, 8), 256, 0, stream>>>(Dm, nmask, mask, gamma, combo);

    // LN1
    ln_kernel<<<ROWS, 320, 0, stream>>>(Z, ln1g, ln1b, Zn);

    // QKV GEMM: Zn(7168x320) @ w_qkv(320x960) + b_qkv -> qkv bf16
    gemm_bt<0><<<dim3(ROWS / 64, 960 / 64), 256, 0, stream>>>(Zn, wqkvT, b_qkv, nullptr,
                                                              (void*)qkv, ROWS, 960, 320);

    // MFMA attention -> leaky_relu -> attn bf16
    attn_mfma<<<BB * 28, 640, 0, stream>>>(qkv, combo, attn);

    // W_O GEMM + residual Z -> Zres f32
    gemm_bt<1><<<dim3(ROWS / 64, 320 / 64), 256, 0, stream>>>(attn, woT, nullptr, Z,
                                                              (void*)Zres, ROWS, 320, 320);

    // LN2
    ln_kernel<<<ROWS, 320, 0, stream>>>(Zres, ln2g, ln2b, Zn2);

    // FFN1: Zn2 @ w1 + b1, relu -> H bf16
    gemm_bt<2><<<dim3(ROWS / 64, 1280 / 64), 256, 0, stream>>>(Zn2, w1T, b1, nullptr,
                                                               (void*)Hbuf, ROWS, 1280, 320);

    // FFN2: H @ w2 + b2 + Zres -> out f32
    gemm_bt<3><<<dim3(ROWS / 64, 320 / 64), 256, 0, stream>>>(Hbuf, w2T, b2, Zres,
                                                              d_out, ROWS, 320, 1280);
}